// Round 4
// baseline (920.925 us; speedup 1.0000x reference)
//
#include <hip/hip_runtime.h>
#include <hip/hip_bf16.h>

// Qriaffine: out[n,i,j] = sum_{a,b,c,d} l1[n,i,a] W[a,b,c,d] l2[n,j,b] h1[n,i,c] h2[n,j,d]
// Plan:
//   P[(n,i)][(a*65+c)] = l1[a]*h1[c]        (8192 x 4225, bf16, pad K->4288)
//   Wt2[(b*65+d)][(a*65+c)] = W[a,b,c,d]    (4225 x 4225, bf16, pad -> 4352 x 4288)
//   Q = P @ Wt2 (NT gemm)                   (8192 x 4352, bf16)
//   R[(n,j)][(b*65+d)] = l2[b]*h2[d]        (8192 x 4352, bf16, built AFTER gemm1)
//   out_n = Q_n @ R_n^T (NT gemm, f32 out)  (8 x 1024 x 1024)
//
// R6: post-mortems of R4/R5 found the real constraint: gfx950's UNIFIED
// VGPR+AGPR file. acc[4][2]=128 AGPRs + ~140 VGPRs = 268 regs -> 1 wave/
// SIMD (R5 occupancy 9.65%). R3 (acc 64, 140 total, 3 waves/SIMD, 30.6%)
// is LDS-read-throughput-bound at ~50% ceiling (measured 39% MfmaUtil).
// => gemm1 = R3 chassis (128x128, 4 waves 2x2, BK=64, 2 barriers/iter)
// but the A operand comes from GLOBAL->REGISTERS per lane (the 32x32x16
// A-frag is 16B contiguous in K = one dwordx4), LDS stages B only:
//   - LDS bytes/block-iter 96KB -> 48KB (0.5 KB/MFMA) -> LDS ceiling ~100%
//   - acc 64 + A-frags 32 + B-frags 32 + addr ~15 ~= 160 regs -> keeps
//     3 waves/SIMD (__launch_bounds__(256,3))
//   - A-loads issue between the two barriers; the existing vmcnt(0) drain
//     covers them (A and B-DMA latencies overlap; no new sync structure)
// gemm2 keeps the R3 128x128 kernel unchanged.

typedef __attribute__((ext_vector_type(8))) short short8;     // 8 bf16 = 4 VGPRs
typedef __attribute__((ext_vector_type(16))) float floatx16;  // MFMA 32x32 acc

#define KP 4288   // padded (a,c) dim: 67*64
#define DP 4352   // padded (b,d) dim: 68*64 = 34*128
#define NROW 8192 // n*L

__device__ __forceinline__ void async_ld16(const void* g, void* l) {
  __builtin_amdgcn_global_load_lds(
      (const __attribute__((address_space(1))) unsigned int*)g,
      (__attribute__((address_space(3))) unsigned int*)l, 16, 0, 0);
}

// ---------------- zero helper (16B granularity) ----------------
__global__ void zero_kernel(float4* __restrict__ p, long n) {
  long i = (long)blockIdx.x * blockDim.x + threadIdx.x;
  long stride = (long)gridDim.x * blockDim.x;
  float4 z = make_float4(0.f, 0.f, 0.f, 0.f);
  for (; i < n; i += stride) p[i] = z;
}

// ---------------- W[a,b,c,d] -> Wt2[(b*65+d)][(a*65+c)] (bf16) ----------------
__global__ void build_wt2(const float* __restrict__ W, __hip_bfloat16* __restrict__ Wt2) {
  __shared__ __hip_bfloat16 tile[65 * 66];
  const int a = blockIdx.x, b = blockIdx.y;
  const float* src = W + (size_t)(a * 65 + b) * 4225;  // contiguous (c,d) plane
  for (int idx = threadIdx.x; idx < 4225; idx += 256) {
    int c = idx / 65, d = idx - c * 65;
    tile[d * 66 + c] = __float2bfloat16(src[idx]);
  }
  __syncthreads();
  for (int idx = threadIdx.x; idx < 4225; idx += 256) {
    int d = idx / 65, c = idx - d * 65;
    Wt2[(size_t)(b * 65 + d) * KP + a * 65 + c] = tile[d * 66 + c];
  }
}

// ---------------- P/R builder: P[row][x*65+y] = layer_row[x] * h_row[y] ----------------
__global__ void build_p(const float* __restrict__ layer, const float* __restrict__ h,
                        __hip_bfloat16* __restrict__ P, int width) {
  const int row = blockIdx.x;
  __shared__ float lv[65], hv[65];
  if (threadIdx.x < 64) lv[threadIdx.x] = layer[(size_t)row * 64 + threadIdx.x];
  if (threadIdx.x == 64) lv[64] = 1.0f;
  if (threadIdx.x < 65) hv[threadIdx.x] = h[(size_t)row * 65 + threadIdx.x];
  __syncthreads();
  for (int base = threadIdx.x * 8; base < width; base += 256 * 8) {
    alignas(16) __hip_bfloat16 tmp[8];
#pragma unroll
    for (int j = 0; j < 8; ++j) {
      int idx = base + j;
      float v = 0.f;
      if (idx < 4225) {
        int x = idx / 65, y = idx - x * 65;
        v = lv[x] * hv[y];
      }
      tmp[j] = __float2bfloat16(v);
    }
    *(float4*)(P + (size_t)row * width + base) = *(const float4*)tmp;
  }
}

// ---------------- gemm1: 128x128 NT GEMM, A from registers, B via LDS ----------------
// C[i][j] = sum_k A[i][k]*B[j][k]. M%128==0, N%128==0, K%64==0.
// 4 waves in 2x2 (each 64x64 = 2x2 tiles of 32x32, acc 64 regs). BK=64.
//
// A-fragments: the 32x32x16 A-frag for lane l is A[row=wm+mt*32+(l&31)]
// [k = k0+ks*16+(l>>5)*8 .. +8] -- 16B contiguous -> global_load_dwordx4
// straight into VGPRs (no LDS round-trip). A panel (1.1 MB/block-row) is
// L2/L3-resident across the 34 N-blocks; intra-block duplication (2 waves
// per wm) hits L1.
// B: staged via global_load_lds x16 into a single 128x64 LDS tile with the
// proven R3 chunk swizzle sg = sl^(row&7).
// Sync per iter (R3 discipline): barrier#1 with lgkmcnt(0) (prev ds_reads
// done before DMA overwrites Bs); A-loads + B-DMA issue between barriers;
// barrier#2 with vmcnt(0) (B resident; A-regs complete). The "memory"
// clobbers pin the A-loads between the barriers.
__global__ __launch_bounds__(256, 3) void gemm_nt_areg(
    const __hip_bfloat16* __restrict__ A, const __hip_bfloat16* __restrict__ B,
    __hip_bfloat16* __restrict__ C, int K, int lda, int ldb, int ldc) {
  __shared__ alignas(16) __hip_bfloat16 Bs[128 * 64];
  const int bn = blockIdx.x * 128;
  const int bm = blockIdx.y * 128;
  const int t = threadIdx.x;
  const int lane = t & 63;
  const int wave = t >> 6;
  const int l31 = lane & 31;
  const int lhi = lane >> 5;
  const int wm = (wave >> 1) * 64;
  const int wn = (wave & 1) * 64;

  // B staging: 1024 16B chunks per 128x64 tile, 4 per thread (R3 pattern)
  const __hip_bfloat16* gB[4];
  __hip_bfloat16* lB[4];
#pragma unroll
  for (int r = 0; r < 4; ++r) {
    int L = r * 256 + t;
    int row = L >> 3, sl = L & 7;
    int sg = sl ^ (row & 7);
    gB[r] = B + (size_t)(bn + row) * ldb + sg * 8;
    lB[r] = Bs + (size_t)(r * 256 + wave * 64) * 8;
  }

  const int x7 = l31 & 7;
  const int rB0 = (wn + l31) * 64, rB1 = (wn + 32 + l31) * 64;

  // per-lane A pointers: row = bm+wm+mt*32+l31, k-base lhi*8
  const __hip_bfloat16* Ap0 = A + (size_t)(bm + wm + l31) * lda + lhi * 8;
  const __hip_bfloat16* Ap1 = Ap0 + (size_t)32 * lda;

  floatx16 acc[2][2] = {};
  const int NT = K >> 6;

  for (int kt = 0; kt < NT; ++kt) {
    const int k0 = kt * 64;
    // barrier 1: all waves' ds_reads of Bs (iter kt-1) complete
    asm volatile("s_waitcnt lgkmcnt(0)\n\ts_barrier" ::: "memory");
    // A-frags for this K-step: 8 x dwordx4 per lane (issued first, so the
    // load latency overlaps the B-DMA latency before the vmcnt(0) drain)
    short8 a[2][4];
#pragma unroll
    for (int ks = 0; ks < 4; ++ks) {
      a[0][ks] = *(const short8*)(Ap0 + k0 + ks * 16);
      a[1][ks] = *(const short8*)(Ap1 + k0 + ks * 16);
    }
    // B tile DMA (global -> LDS)
#pragma unroll
    for (int r = 0; r < 4; ++r) async_ld16(gB[r] + k0, lB[r]);
    // barrier 2: B resident in LDS (and A-regs complete, same counter)
    asm volatile("s_waitcnt vmcnt(0)\n\ts_barrier" ::: "memory");

#pragma unroll
    for (int ks = 0; ks < 4; ++ks) {
      const int pc = ((ks * 2 + lhi) ^ x7) * 8;  // swizzled chunk -> elem off
      short8 b0 = *(const short8*)(&Bs[rB0 + pc]);
      short8 b1 = *(const short8*)(&Bs[rB1 + pc]);
      acc[0][0] = __builtin_amdgcn_mfma_f32_32x32x16_bf16(a[0][ks], b0, acc[0][0], 0, 0, 0);
      acc[0][1] = __builtin_amdgcn_mfma_f32_32x32x16_bf16(a[0][ks], b1, acc[0][1], 0, 0, 0);
      acc[1][0] = __builtin_amdgcn_mfma_f32_32x32x16_bf16(a[1][ks], b0, acc[1][0], 0, 0, 0);
      acc[1][1] = __builtin_amdgcn_mfma_f32_32x32x16_bf16(a[1][ks], b1, acc[1][1], 0, 0, 0);
    }
  }

  // C/D layout (verified m74/m101): col = lane&31,
  // row = (reg&3) + 8*(reg>>2) + 4*(lane>>5)
#pragma unroll
  for (int mt = 0; mt < 2; ++mt)
#pragma unroll
    for (int nt = 0; nt < 2; ++nt)
#pragma unroll
      for (int reg = 0; reg < 16; ++reg) {
        int row = bm + wm + mt * 32 + (reg & 3) + 8 * (reg >> 2) + 4 * lhi;
        int col = bn + wn + nt * 32 + l31;
        C[(size_t)row * ldc + col] = __float2bfloat16(acc[mt][nt][reg]);
      }
}

// ---------------- NT GEMM (R3 kernel, kept for gemm2) ----------------
// A: M x K (lda), B: N x K (ldb), row-major bf16, K % 64 == 0.
// 128x128 block tile, 4 waves each 64x64 = 2x2 tiles of 32x32, BK=64,
// mfma_f32_32x32x16_bf16. Staging via global_load_lds x16, XOR-swizzled LDS.
template <int STORE_BF16>
__global__ __launch_bounds__(256) void gemm_nt(
    const __hip_bfloat16* __restrict__ A, const __hip_bfloat16* __restrict__ B,
    void* __restrict__ Cv, int K, int lda, int ldb, int ldc,
    long sA, long sB, long sC) {
  __shared__ alignas(16) __hip_bfloat16 As[128 * 64];
  __shared__ alignas(16) __hip_bfloat16 Bs[128 * 64];
  const int z = blockIdx.z;
  A += (long)z * sA;
  B += (long)z * sB;
  const int bm = blockIdx.y * 128;
  const int bn = blockIdx.x * 128;
  const int t = threadIdx.x;
  const int lane = t & 63;
  const int wave = t >> 6;
  const int l31 = lane & 31;
  const int lhi = lane >> 5;
  const int wm = (wave >> 1) * 64;
  const int wn = (wave & 1) * 64;

  const __hip_bfloat16* gA[4];
  const __hip_bfloat16* gB[4];
  __hip_bfloat16* lA[4];
  __hip_bfloat16* lB[4];
#pragma unroll
  for (int r = 0; r < 4; ++r) {
    int L = r * 256 + t;
    int row = L >> 3, sl = L & 7;
    int sg = sl ^ (row & 7);
    gA[r] = A + (size_t)(bm + row) * lda + sg * 8;
    gB[r] = B + (size_t)(bn + row) * ldb + sg * 8;
    lA[r] = As + (size_t)(r * 256 + wave * 64) * 8;
    lB[r] = Bs + (size_t)(r * 256 + wave * 64) * 8;
  }

  const int x7 = l31 & 7;
  const int rA0 = (wm + l31) * 64, rA1 = (wm + 32 + l31) * 64;
  const int rB0 = (wn + l31) * 64, rB1 = (wn + 32 + l31) * 64;

  floatx16 acc[2][2] = {};

  for (int k0 = 0; k0 < K; k0 += 64) {
    __syncthreads();
#pragma unroll
    for (int r = 0; r < 4; ++r) {
      async_ld16(gA[r] + k0, lA[r]);
      async_ld16(gB[r] + k0, lB[r]);
    }
    __syncthreads();

#pragma unroll
    for (int ks = 0; ks < 4; ++ks) {
      const int pc = ((ks * 2 + lhi) ^ x7) * 8;
      short8 a0 = *(const short8*)(&As[rA0 + pc]);
      short8 a1 = *(const short8*)(&As[rA1 + pc]);
      short8 b0 = *(const short8*)(&Bs[rB0 + pc]);
      short8 b1 = *(const short8*)(&Bs[rB1 + pc]);
      acc[0][0] = __builtin_amdgcn_mfma_f32_32x32x16_bf16(a0, b0, acc[0][0], 0, 0, 0);
      acc[0][1] = __builtin_amdgcn_mfma_f32_32x32x16_bf16(a0, b1, acc[0][1], 0, 0, 0);
      acc[1][0] = __builtin_amdgcn_mfma_f32_32x32x16_bf16(a1, b0, acc[1][0], 0, 0, 0);
      acc[1][1] = __builtin_amdgcn_mfma_f32_32x32x16_bf16(a1, b1, acc[1][1], 0, 0, 0);
    }
  }

  if (STORE_BF16) {
    __hip_bfloat16* C = (__hip_bfloat16*)Cv + (long)z * sC;
#pragma unroll
    for (int mt = 0; mt < 2; ++mt)
#pragma unroll
      for (int nt = 0; nt < 2; ++nt)
#pragma unroll
        for (int reg = 0; reg < 16; ++reg) {
          int row = bm + wm + mt * 32 + (reg & 3) + 8 * (reg >> 2) + 4 * lhi;
          int col = bn + wn + nt * 32 + l31;
          C[(size_t)row * ldc + col] = __float2bfloat16(acc[mt][nt][reg]);
        }
  } else {
    float* C = (float*)Cv + (long)z * sC;
#pragma unroll
    for (int mt = 0; mt < 2; ++mt)
#pragma unroll
      for (int nt = 0; nt < 2; ++nt)
#pragma unroll
        for (int reg = 0; reg < 16; ++reg) {
          int row = bm + wm + mt * 32 + (reg & 3) + 8 * (reg >> 2) + 4 * lhi;
          int col = bn + wn + nt * 32 + l31;
          C[(size_t)row * ldc + col] = acc[mt][nt][reg];
        }
  }
}

extern "C" void kernel_launch(void* const* d_in, const int* in_sizes, int n_in,
                              void* d_out, int out_size, void* d_ws, size_t ws_size,
                              hipStream_t stream) {
  const float* layer1 = (const float*)d_in[0];
  const float* layer2 = (const float*)d_in[1];
  const float* h1 = (const float*)d_in[3];
  const float* h2 = (const float*)d_in[4];
  const float* W = (const float*)d_in[6];
  float* out = (float*)d_out;

  // workspace layout (bytes), total high-water 178,880,512:
  //   [0 .. 70,254,592)            P  (8192*4288*2)   -- later reused for R
  //   [70,254,592 .. 107,577,344)  Wt2 (4352*4288*2)
  //   [107,577,344 .. 178,880,512) Q  (8192*4352*2)
  char* ws = (char*)d_ws;
  __hip_bfloat16* P = (__hip_bfloat16*)(ws);
  __hip_bfloat16* Wt2 = (__hip_bfloat16*)(ws + 70254592ULL);
  __hip_bfloat16* Q = (__hip_bfloat16*)(ws + 107577344ULL);
  __hip_bfloat16* R = (__hip_bfloat16*)(ws);  // reuses P/Wt2 region

  // 1) zero Wt2 (covers pad rows/cols; real entries overwritten next)
  zero_kernel<<<2048, 256, 0, stream>>>((float4*)Wt2, (long)DP * KP * 2 / 16);
  // 2) transpose+cast W
  build_wt2<<<dim3(65, 65), 256, 0, stream>>>(W, Wt2);
  // 3) P
  build_p<<<NROW, 256, 0, stream>>>(layer1, h1, P, KP);
  // 4) Q = P @ Wt2 (NT): M=8192, N=4352, K=4288 — A-in-registers kernel
  gemm_nt_areg<<<dim3(DP / 128, NROW / 128), 256, 0, stream>>>(
      P, Wt2, Q, KP, KP, KP, DP);
  // 5) R (over the now-dead P/Wt2 region)
  build_p<<<NROW, 256, 0, stream>>>(layer2, h2, R, DP);
  // 6) out_n = Q_n @ R_n^T: M=N=1024, K=4352, batched over n=8
  gemm_nt<0><<<dim3(1024 / 128, 1024 / 128, 8), 256, 0, stream>>>(
      Q, R, out, DP, DP, DP, 1024, 1024L * DP, 1024L * DP, 1024L * 1024);
}

// Round 5
// 592.305 us; speedup vs baseline: 1.5548x; 1.5548x over previous
//
#include <hip/hip_runtime.h>
#include <hip/hip_bf16.h>

// Qriaffine: out[n,i,j] = sum_{a,b,c,d} l1[n,i,a] W[a,b,c,d] l2[n,j,b] h1[n,i,c] h2[n,j,d]
// Plan:
//   P[(n,i)][(a*65+c)] = l1[a]*h1[c]        (8192 x 4225, bf16, pad K->4288)
//   Wt2[(b*65+d)][(a*65+c)] = W[a,b,c,d]    (4225 x 4225, bf16, pad -> 4352 x 4288)
//   Q = P @ Wt2 (NT gemm)                   (8192 x 4352, bf16)
//   R[(n,j)][(b*65+d)] = l2[b]*h2[d]        (8192 x 4352, bf16, built AFTER gemm1)
//   out_n = Q_n @ R_n^T (NT gemm, f32 out)  (8 x 1024 x 1024)
//
// R7: R4/R5/R6 all lost to the R3 structure (620/469/704 vs 357us) --
// restructures and operand-path changes are dead ends; R3's 2-barrier
// 128x128 kernel is at its structural ceiling (~856 TF) and every in-
// structure knob except LOCALITY is exhausted. R3's counters show 643MB
// HBM fetch vs ~110MB compulsory (6x re-read): the per-iter vmcnt(0)
// drain pays full HBM latency instead of L2/L3 latency.
// Changes vs R3 (all safe, no sync-structure edits):
//   1. gemm1 block remap (bijective): XCD k (linear-dispatch mod 8) owns
//      M-rows [8k,8k+8); x swept in groups of 9 -> per-XCD concurrent
//      working set ~22MB (A 8.9 + B ~13) instead of scattered ~60MB.
//   2. zero only Wt2's pad region (1.6MB) instead of all 37MB.
//   3. gemm2 K=4288 (cols 4225..4287 of Q,R are exact zeros).

typedef __attribute__((ext_vector_type(8))) short short8;     // 8 bf16 = 4 VGPRs
typedef __attribute__((ext_vector_type(16))) float floatx16;  // MFMA 32x32 acc

#define KP 4288   // padded (a,c) dim: 67*64
#define DP 4352   // padded (b,d) dim: 68*64 = 34*128
#define NROW 8192 // n*L

__device__ __forceinline__ void async_ld16(const void* g, void* l) {
  __builtin_amdgcn_global_load_lds(
      (const __attribute__((address_space(1))) unsigned int*)g,
      (__attribute__((address_space(3))) unsigned int*)l, 16, 0, 0);
}

// ---------------- pad-only zero for Wt2 ----------------
// real entries (rows 0..4224 x cols 0..4224) are all written by build_wt2;
// pads must be finite (0) so MFMA K-sums stay clean:
//   region A: rows 4225..4351 (127 rows), full KP width
//   region B: rows 0..4224, cols 4225..4287 (63 cols)
__global__ void zero_pad_wt2(__hip_bfloat16* __restrict__ Wt2) {
  const int ROWPAD = 127 * KP;    // 544,576
  const int COLPAD = 4225 * 63;   // 266,175
  const int total = ROWPAD + COLPAD;
  const __hip_bfloat16 z = __float2bfloat16(0.f);
  for (int id = blockIdx.x * 256 + threadIdx.x; id < total;
       id += gridDim.x * 256) {
    if (id < ROWPAD) {
      int row = 4225 + id / KP, col = id % KP;
      Wt2[(size_t)row * KP + col] = z;
    } else {
      int j = id - ROWPAD;
      int row = j / 63, col = 4225 + j % 63;
      Wt2[(size_t)row * KP + col] = z;
    }
  }
}

// ---------------- W[a,b,c,d] -> Wt2[(b*65+d)][(a*65+c)] (bf16) ----------------
__global__ void build_wt2(const float* __restrict__ W, __hip_bfloat16* __restrict__ Wt2) {
  __shared__ __hip_bfloat16 tile[65 * 66];
  const int a = blockIdx.x, b = blockIdx.y;
  const float* src = W + (size_t)(a * 65 + b) * 4225;  // contiguous (c,d) plane
  for (int idx = threadIdx.x; idx < 4225; idx += 256) {
    int c = idx / 65, d = idx - c * 65;
    tile[d * 66 + c] = __float2bfloat16(src[idx]);
  }
  __syncthreads();
  for (int idx = threadIdx.x; idx < 4225; idx += 256) {
    int d = idx / 65, c = idx - d * 65;
    Wt2[(size_t)(b * 65 + d) * KP + a * 65 + c] = tile[d * 66 + c];
  }
}

// ---------------- P/R builder: P[row][x*65+y] = layer_row[x] * h_row[y] ----------------
__global__ void build_p(const float* __restrict__ layer, const float* __restrict__ h,
                        __hip_bfloat16* __restrict__ P, int width) {
  const int row = blockIdx.x;
  __shared__ float lv[65], hv[65];
  if (threadIdx.x < 64) lv[threadIdx.x] = layer[(size_t)row * 64 + threadIdx.x];
  if (threadIdx.x == 64) lv[64] = 1.0f;
  if (threadIdx.x < 65) hv[threadIdx.x] = h[(size_t)row * 65 + threadIdx.x];
  __syncthreads();
  for (int base = threadIdx.x * 8; base < width; base += 256 * 8) {
    alignas(16) __hip_bfloat16 tmp[8];
#pragma unroll
    for (int j = 0; j < 8; ++j) {
      int idx = base + j;
      float v = 0.f;
      if (idx < 4225) {
        int x = idx / 65, y = idx - x * 65;
        v = lv[x] * hv[y];
      }
      tmp[j] = __float2bfloat16(v);
    }
    *(float4*)(P + (size_t)row * width + base) = *(const float4*)tmp;
  }
}

// ---------------- NT GEMM (proven R3 kernel) ----------------
// A: M x K (lda), B: N x K (ldb), row-major bf16, K % 64 == 0.
// 128x128 block tile, 4 waves each 64x64 = 2x2 tiles of 32x32, BK=64,
// mfma_f32_32x32x16_bf16. Staging via global_load_lds x16, XOR-swizzled LDS.
// SWZ=1 (gemm1 only; requires grid exactly (34,64)): locality remap --
// hardware dispatch is linear round-robin over XCDs (orig mod 8), so give
// XCD k the M-rows [8k,8k+8) and sweep x in groups of 9:
//   xcd = orig&7; idx = orig>>3 in [0,272)
//   xg = idx<216 ? idx/72 : 3; r = idx - xg*72
//   bx = xg*9 + (r>>3)  in [0,34);  by = xcd*8 + (r&7)  in [0,64)
// Bijective (inverse: xcd=by>>3, xg=bx/9, r=(bx-9*xg)*8+(by&7)).
template <int STORE_BF16, int SWZ>
__global__ __launch_bounds__(256) void gemm_nt(
    const __hip_bfloat16* __restrict__ A, const __hip_bfloat16* __restrict__ B,
    void* __restrict__ Cv, int K, int lda, int ldb, int ldc,
    long sA, long sB, long sC) {
  __shared__ alignas(16) __hip_bfloat16 As[128 * 64];
  __shared__ alignas(16) __hip_bfloat16 Bs[128 * 64];
  const int z = blockIdx.z;
  A += (long)z * sA;
  B += (long)z * sB;
  int bx = blockIdx.x, by = blockIdx.y;
  if (SWZ) {
    int orig = blockIdx.x + 34 * blockIdx.y;  // grid (34,64) -> 0..2175
    int xcd = orig & 7;
    int idx = orig >> 3;                      // 0..271
    int xg = (idx < 216) ? (idx / 72) : 3;
    int r = idx - xg * 72;
    bx = xg * 9 + (r >> 3);
    by = (xcd << 3) + (r & 7);
  }
  const int bm = by * 128;
  const int bn = bx * 128;
  const int t = threadIdx.x;
  const int lane = t & 63;
  const int wave = t >> 6;
  const int l31 = lane & 31;
  const int lhi = lane >> 5;
  const int wm = (wave >> 1) * 64;
  const int wn = (wave & 1) * 64;

  const __hip_bfloat16* gA[4];
  const __hip_bfloat16* gB[4];
  __hip_bfloat16* lA[4];
  __hip_bfloat16* lB[4];
#pragma unroll
  for (int r = 0; r < 4; ++r) {
    int L = r * 256 + t;
    int row = L >> 3, sl = L & 7;
    int sg = sl ^ (row & 7);
    gA[r] = A + (size_t)(bm + row) * lda + sg * 8;
    gB[r] = B + (size_t)(bn + row) * ldb + sg * 8;
    lA[r] = As + (size_t)(r * 256 + wave * 64) * 8;
    lB[r] = Bs + (size_t)(r * 256 + wave * 64) * 8;
  }

  const int x7 = l31 & 7;
  const int rA0 = (wm + l31) * 64, rA1 = (wm + 32 + l31) * 64;
  const int rB0 = (wn + l31) * 64, rB1 = (wn + 32 + l31) * 64;

  floatx16 acc[2][2] = {};

  for (int k0 = 0; k0 < K; k0 += 64) {
    __syncthreads();
#pragma unroll
    for (int r = 0; r < 4; ++r) {
      async_ld16(gA[r] + k0, lA[r]);
      async_ld16(gB[r] + k0, lB[r]);
    }
    __syncthreads();

#pragma unroll
    for (int ks = 0; ks < 4; ++ks) {
      const int pc = ((ks * 2 + lhi) ^ x7) * 8;
      short8 a0 = *(const short8*)(&As[rA0 + pc]);
      short8 a1 = *(const short8*)(&As[rA1 + pc]);
      short8 b0 = *(const short8*)(&Bs[rB0 + pc]);
      short8 b1 = *(const short8*)(&Bs[rB1 + pc]);
      acc[0][0] = __builtin_amdgcn_mfma_f32_32x32x16_bf16(a0, b0, acc[0][0], 0, 0, 0);
      acc[0][1] = __builtin_amdgcn_mfma_f32_32x32x16_bf16(a0, b1, acc[0][1], 0, 0, 0);
      acc[1][0] = __builtin_amdgcn_mfma_f32_32x32x16_bf16(a1, b0, acc[1][0], 0, 0, 0);
      acc[1][1] = __builtin_amdgcn_mfma_f32_32x32x16_bf16(a1, b1, acc[1][1], 0, 0, 0);
    }
  }

  // C/D layout (verified m74/m101): col = lane&31,
  // row = (reg&3) + 8*(reg>>2) + 4*(lane>>5)
  if (STORE_BF16) {
    __hip_bfloat16* C = (__hip_bfloat16*)Cv + (long)z * sC;
#pragma unroll
    for (int mt = 0; mt < 2; ++mt)
#pragma unroll
      for (int nt = 0; nt < 2; ++nt)
#pragma unroll
        for (int reg = 0; reg < 16; ++reg) {
          int row = bm + wm + mt * 32 + (reg & 3) + 8 * (reg >> 2) + 4 * lhi;
          int col = bn + wn + nt * 32 + l31;
          C[(size_t)row * ldc + col] = __float2bfloat16(acc[mt][nt][reg]);
        }
  } else {
    float* C = (float*)Cv + (long)z * sC;
#pragma unroll
    for (int mt = 0; mt < 2; ++mt)
#pragma unroll
      for (int nt = 0; nt < 2; ++nt)
#pragma unroll
        for (int reg = 0; reg < 16; ++reg) {
          int row = bm + wm + mt * 32 + (reg & 3) + 8 * (reg >> 2) + 4 * lhi;
          int col = bn + wn + nt * 32 + l31;
          C[(size_t)row * ldc + col] = acc[mt][nt][reg];
        }
  }
}

extern "C" void kernel_launch(void* const* d_in, const int* in_sizes, int n_in,
                              void* d_out, int out_size, void* d_ws, size_t ws_size,
                              hipStream_t stream) {
  const float* layer1 = (const float*)d_in[0];
  const float* layer2 = (const float*)d_in[1];
  const float* h1 = (const float*)d_in[3];
  const float* h2 = (const float*)d_in[4];
  const float* W = (const float*)d_in[6];
  float* out = (float*)d_out;

  // workspace layout (bytes), total high-water 178,880,512:
  //   [0 .. 70,254,592)            P  (8192*4288*2)   -- later reused for R
  //   [70,254,592 .. 107,577,344)  Wt2 (4352*4288*2)
  //   [107,577,344 .. 178,880,512) Q  (8192*4352*2)
  char* ws = (char*)d_ws;
  __hip_bfloat16* P = (__hip_bfloat16*)(ws);
  __hip_bfloat16* Wt2 = (__hip_bfloat16*)(ws + 70254592ULL);
  __hip_bfloat16* Q = (__hip_bfloat16*)(ws + 107577344ULL);
  __hip_bfloat16* R = (__hip_bfloat16*)(ws);  // reuses P/Wt2 region

  // 1) zero Wt2 pads only (real entries all overwritten by build_wt2)
  zero_pad_wt2<<<1024, 256, 0, stream>>>(Wt2);
  // 2) transpose+cast W
  build_wt2<<<dim3(65, 65), 256, 0, stream>>>(W, Wt2);
  // 3) P
  build_p<<<NROW, 256, 0, stream>>>(layer1, h1, P, KP);
  // 4) Q = P @ Wt2 (NT): M=8192, N=4352, K=4288 — R3 kernel + locality remap
  gemm_nt<1, 1><<<dim3(DP / 128, NROW / 128, 1), 256, 0, stream>>>(
      P, Wt2, Q, KP, KP, KP, DP, 0, 0, 0);
  // 5) R (over the now-dead P/Wt2 region)
  build_p<<<NROW, 256, 0, stream>>>(layer2, h2, R, DP);
  // 6) out_n = Q_n @ R_n^T: M=N=1024, K=4288 (cols 4225..4287 are zeros),
  //    batched over n=8
  gemm_nt<0, 0><<<dim3(1024 / 128, 1024 / 128, 8), 256, 0, stream>>>(
      Q, R, out, 4288, DP, DP, 1024, 1024L * DP, 1024L * DP, 1024L * 1024);
}

// Round 6
// 577.684 us; speedup vs baseline: 1.5942x; 1.0253x over previous
//
#include <hip/hip_runtime.h>
#include <hip/hip_bf16.h>

// Qriaffine: out[n,i,j] = sum_{a,b,c,d} l1[n,i,a] W[a,b,c,d] l2[n,j,b] h1[n,i,c] h2[n,j,d]
// Plan:
//   P[(n,i)][(a*65+c)] = l1[a]*h1[c]        (8192 x 4225, bf16, pad K->4288)
//   Wt2[(b*65+d)][(a*65+c)] = W[a,b,c,d]    (4225 x 4225, bf16, pad -> 4352 x 4288)
//   Q = P @ Wt2 (NT gemm)                   (8192 x 4352, bf16)
//   R[(n,j)][(b*65+d)] = l2[b]*h2[d]        (8192 x 4352, bf16, built AFTER gemm1)
//   out_n = Q_n @ R_n^T (NT gemm, f32 out)  (8 x 1024 x 1024)
//
// R8: R7's XCD remap verified (gemm1 FETCH 643->272MB) but gemm1 time is
// structure-limited at ~874 TF (m97-class ceiling) -- locked. This round
// applies the SAME verified remap mechanism to gemm2 (batch-per-XCD:
// z'=orig&7 -> per-XCD working set 79MB -> 17.8MB, A-panel L2-hot) and
// consolidates build_p to 4 rows/block (grid 8192->2048). gemm1/build_wt2/
// zero_pad byte-identical to R7.

typedef __attribute__((ext_vector_type(8))) short short8;     // 8 bf16 = 4 VGPRs
typedef __attribute__((ext_vector_type(16))) float floatx16;  // MFMA 32x32 acc

#define KP 4288   // padded (a,c) dim: 67*64
#define DP 4352   // padded (b,d) dim: 68*64 = 34*128
#define NROW 8192 // n*L

__device__ __forceinline__ void async_ld16(const void* g, void* l) {
  __builtin_amdgcn_global_load_lds(
      (const __attribute__((address_space(1))) unsigned int*)g,
      (__attribute__((address_space(3))) unsigned int*)l, 16, 0, 0);
}

// ---------------- pad-only zero for Wt2 ----------------
// real entries (rows 0..4224 x cols 0..4224) are all written by build_wt2;
// pads must be finite (0) so MFMA K-sums stay clean:
//   region A: rows 4225..4351 (127 rows), full KP width
//   region B: rows 0..4224, cols 4225..4287 (63 cols)
__global__ void zero_pad_wt2(__hip_bfloat16* __restrict__ Wt2) {
  const int ROWPAD = 127 * KP;    // 544,576
  const int COLPAD = 4225 * 63;   // 266,175
  const int total = ROWPAD + COLPAD;
  const __hip_bfloat16 z = __float2bfloat16(0.f);
  for (int id = blockIdx.x * 256 + threadIdx.x; id < total;
       id += gridDim.x * 256) {
    if (id < ROWPAD) {
      int row = 4225 + id / KP, col = id % KP;
      Wt2[(size_t)row * KP + col] = z;
    } else {
      int j = id - ROWPAD;
      int row = j / 63, col = 4225 + j % 63;
      Wt2[(size_t)row * KP + col] = z;
    }
  }
}

// ---------------- W[a,b,c,d] -> Wt2[(b*65+d)][(a*65+c)] (bf16) ----------------
__global__ void build_wt2(const float* __restrict__ W, __hip_bfloat16* __restrict__ Wt2) {
  __shared__ __hip_bfloat16 tile[65 * 66];
  const int a = blockIdx.x, b = blockIdx.y;
  const float* src = W + (size_t)(a * 65 + b) * 4225;  // contiguous (c,d) plane
  for (int idx = threadIdx.x; idx < 4225; idx += 256) {
    int c = idx / 65, d = idx - c * 65;
    tile[d * 66 + c] = __float2bfloat16(src[idx]);
  }
  __syncthreads();
  for (int idx = threadIdx.x; idx < 4225; idx += 256) {
    int d = idx / 65, c = idx - d * 65;
    Wt2[(size_t)(b * 65 + d) * KP + a * 65 + c] = tile[d * 66 + c];
  }
}

// ---------------- P/R builder: P[row][x*65+y] = layer_row[x] * h_row[y] ----------------
// 4 rows per block (grid = NROW/4) to amortize block setup.
__global__ void build_p(const float* __restrict__ layer, const float* __restrict__ h,
                        __hip_bfloat16* __restrict__ P, int width) {
  const int row0 = blockIdx.x * 4;
  __shared__ float lv[4][65], hv[4][65];
  for (int i = threadIdx.x; i < 260; i += 256) {
    int rr = i / 65, x = i - rr * 65;
    lv[rr][x] = (x < 64) ? layer[(size_t)(row0 + rr) * 64 + x] : 1.0f;
    hv[rr][x] = h[(size_t)(row0 + rr) * 65 + x];
  }
  __syncthreads();
#pragma unroll
  for (int rr = 0; rr < 4; ++rr) {
    const size_t rowbase = (size_t)(row0 + rr) * width;
    for (int base = threadIdx.x * 8; base < width; base += 256 * 8) {
      alignas(16) __hip_bfloat16 tmp[8];
#pragma unroll
      for (int j = 0; j < 8; ++j) {
        int idx = base + j;
        float v = 0.f;
        if (idx < 4225) {
          int x = idx / 65, y = idx - x * 65;
          v = lv[rr][x] * hv[rr][y];
        }
        tmp[j] = __float2bfloat16(v);
      }
      *(float4*)(P + rowbase + base) = *(const float4*)tmp;
    }
  }
}

// ---------------- NT GEMM (proven R3 kernel) ----------------
// A: M x K (lda), B: N x K (ldb), row-major bf16, K % 64 == 0.
// 128x128 block tile, 4 waves each 64x64 = 2x2 tiles of 32x32, BK=64,
// mfma_f32_32x32x16_bf16. Staging via global_load_lds x16, XOR-swizzled LDS.
// SWZ=1 (gemm1; grid exactly (34,64,1)): locality remap -- XCD k
// (linear-dispatch mod 8) owns M-rows [8k,8k+8); x swept in groups of 9.
// Bijective (verified R7: FETCH 643->272MB).
// SWZ=2 (gemm2; grid exactly (8,8,8)): batch-per-XCD remap -- XCD k owns
// batch z=k entirely (64 tiles); within, bx fastest so the by-row A-panel
// (1.1MB) stays L2-hot. orig = bx + 8*by + 64*bz; z'=orig&7,
// bx'=(orig>>3)&7, by'=orig>>6. Bijective.
template <int STORE_BF16, int SWZ>
__global__ __launch_bounds__(256) void gemm_nt(
    const __hip_bfloat16* __restrict__ A, const __hip_bfloat16* __restrict__ B,
    void* __restrict__ Cv, int K, int lda, int ldb, int ldc,
    long sA, long sB, long sC) {
  __shared__ alignas(16) __hip_bfloat16 As[128 * 64];
  __shared__ alignas(16) __hip_bfloat16 Bs[128 * 64];
  int bx = blockIdx.x, by = blockIdx.y, z = blockIdx.z;
  if (SWZ == 1) {
    int orig = blockIdx.x + 34 * blockIdx.y;  // grid (34,64) -> 0..2175
    int xcd = orig & 7;
    int idx = orig >> 3;                      // 0..271
    int xg = (idx < 216) ? (idx / 72) : 3;
    int r = idx - xg * 72;
    bx = xg * 9 + (r >> 3);
    by = (xcd << 3) + (r & 7);
  } else if (SWZ == 2) {
    int orig = blockIdx.x + 8 * blockIdx.y + 64 * blockIdx.z;  // 0..511
    z = orig & 7;
    int r = orig >> 3;  // 0..63
    bx = r & 7;
    by = r >> 3;
  }
  A += (long)z * sA;
  B += (long)z * sB;
  const int bm = by * 128;
  const int bn = bx * 128;
  const int t = threadIdx.x;
  const int lane = t & 63;
  const int wave = t >> 6;
  const int l31 = lane & 31;
  const int lhi = lane >> 5;
  const int wm = (wave >> 1) * 64;
  const int wn = (wave & 1) * 64;

  const __hip_bfloat16* gA[4];
  const __hip_bfloat16* gB[4];
  __hip_bfloat16* lA[4];
  __hip_bfloat16* lB[4];
#pragma unroll
  for (int r = 0; r < 4; ++r) {
    int L = r * 256 + t;
    int row = L >> 3, sl = L & 7;
    int sg = sl ^ (row & 7);
    gA[r] = A + (size_t)(bm + row) * lda + sg * 8;
    gB[r] = B + (size_t)(bn + row) * ldb + sg * 8;
    lA[r] = As + (size_t)(r * 256 + wave * 64) * 8;
    lB[r] = Bs + (size_t)(r * 256 + wave * 64) * 8;
  }

  const int x7 = l31 & 7;
  const int rA0 = (wm + l31) * 64, rA1 = (wm + 32 + l31) * 64;
  const int rB0 = (wn + l31) * 64, rB1 = (wn + 32 + l31) * 64;

  floatx16 acc[2][2] = {};

  for (int k0 = 0; k0 < K; k0 += 64) {
    __syncthreads();
#pragma unroll
    for (int r = 0; r < 4; ++r) {
      async_ld16(gA[r] + k0, lA[r]);
      async_ld16(gB[r] + k0, lB[r]);
    }
    __syncthreads();

#pragma unroll
    for (int ks = 0; ks < 4; ++ks) {
      const int pc = ((ks * 2 + lhi) ^ x7) * 8;
      short8 a0 = *(const short8*)(&As[rA0 + pc]);
      short8 a1 = *(const short8*)(&As[rA1 + pc]);
      short8 b0 = *(const short8*)(&Bs[rB0 + pc]);
      short8 b1 = *(const short8*)(&Bs[rB1 + pc]);
      acc[0][0] = __builtin_amdgcn_mfma_f32_32x32x16_bf16(a0, b0, acc[0][0], 0, 0, 0);
      acc[0][1] = __builtin_amdgcn_mfma_f32_32x32x16_bf16(a0, b1, acc[0][1], 0, 0, 0);
      acc[1][0] = __builtin_amdgcn_mfma_f32_32x32x16_bf16(a1, b0, acc[1][0], 0, 0, 0);
      acc[1][1] = __builtin_amdgcn_mfma_f32_32x32x16_bf16(a1, b1, acc[1][1], 0, 0, 0);
    }
  }

  // C/D layout (verified m74/m101): col = lane&31,
  // row = (reg&3) + 8*(reg>>2) + 4*(lane>>5)
  if (STORE_BF16) {
    __hip_bfloat16* C = (__hip_bfloat16*)Cv + (long)z * sC;
#pragma unroll
    for (int mt = 0; mt < 2; ++mt)
#pragma unroll
      for (int nt = 0; nt < 2; ++nt)
#pragma unroll
        for (int reg = 0; reg < 16; ++reg) {
          int row = bm + wm + mt * 32 + (reg & 3) + 8 * (reg >> 2) + 4 * lhi;
          int col = bn + wn + nt * 32 + l31;
          C[(size_t)row * ldc + col] = __float2bfloat16(acc[mt][nt][reg]);
        }
  } else {
    float* C = (float*)Cv + (long)z * sC;
#pragma unroll
    for (int mt = 0; mt < 2; ++mt)
#pragma unroll
      for (int nt = 0; nt < 2; ++nt)
#pragma unroll
        for (int reg = 0; reg < 16; ++reg) {
          int row = bm + wm + mt * 32 + (reg & 3) + 8 * (reg >> 2) + 4 * lhi;
          int col = bn + wn + nt * 32 + l31;
          C[(size_t)row * ldc + col] = acc[mt][nt][reg];
        }
  }
}

extern "C" void kernel_launch(void* const* d_in, const int* in_sizes, int n_in,
                              void* d_out, int out_size, void* d_ws, size_t ws_size,
                              hipStream_t stream) {
  const float* layer1 = (const float*)d_in[0];
  const float* layer2 = (const float*)d_in[1];
  const float* h1 = (const float*)d_in[3];
  const float* h2 = (const float*)d_in[4];
  const float* W = (const float*)d_in[6];
  float* out = (float*)d_out;

  // workspace layout (bytes), total high-water 178,880,512:
  //   [0 .. 70,254,592)            P  (8192*4288*2)   -- later reused for R
  //   [70,254,592 .. 107,577,344)  Wt2 (4352*4288*2)
  //   [107,577,344 .. 178,880,512) Q  (8192*4352*2)
  char* ws = (char*)d_ws;
  __hip_bfloat16* P = (__hip_bfloat16*)(ws);
  __hip_bfloat16* Wt2 = (__hip_bfloat16*)(ws + 70254592ULL);
  __hip_bfloat16* Q = (__hip_bfloat16*)(ws + 107577344ULL);
  __hip_bfloat16* R = (__hip_bfloat16*)(ws);  // reuses P/Wt2 region

  // 1) zero Wt2 pads only (real entries all overwritten by build_wt2)
  zero_pad_wt2<<<1024, 256, 0, stream>>>(Wt2);
  // 2) transpose+cast W
  build_wt2<<<dim3(65, 65), 256, 0, stream>>>(W, Wt2);
  // 3) P (4 rows per block)
  build_p<<<NROW / 4, 256, 0, stream>>>(layer1, h1, P, KP);
  // 4) Q = P @ Wt2 (NT): M=8192, N=4352, K=4288 — R3 kernel + locality remap
  gemm_nt<1, 1><<<dim3(DP / 128, NROW / 128, 1), 256, 0, stream>>>(
      P, Wt2, Q, KP, KP, KP, DP, 0, 0, 0);
  // 5) R (over the now-dead P/Wt2 region)
  build_p<<<NROW / 4, 256, 0, stream>>>(layer2, h2, R, DP);
  // 6) out_n = Q_n @ R_n^T: M=N=1024, K=4288 (cols 4225..4287 are zeros),
  //    batched over n=8, batch-per-XCD remap
  gemm_nt<0, 2><<<dim3(1024 / 128, 1024 / 128, 8), 256, 0, stream>>>(
      Q, R, out, 4288, DP, DP, 1024, 1024L * DP, 1024L * DP, 1024L * 1024);
}